// Round 8
// baseline (226.906 us; speedup 1.0000x reference)
//
#include <hip/hip_runtime.h>
#include <stdint.h>

#define BATCH 32
#define IMG 512
#define CH 3
#define GOUT 64
#define ROWB (IMG*CH)   // 1536 floats per image row
#define GPLANE ((size_t)BATCH*CH*GOUT*IMG)   // one bf16 k-partial of planar g

typedef __attribute__((ext_vector_type(8))) short  short8;
typedef __attribute__((ext_vector_type(4))) float  floatx4;

__device__ __forceinline__ unsigned short f2bf(float x) {
    unsigned u = __builtin_bit_cast(unsigned, x);
    u += 0x7FFFu + ((u >> 16) & 1u);
    return (unsigned short)(u >> 16);
}
__device__ __forceinline__ float b2f(short s) {
    return __builtin_bit_cast(float, ((unsigned)(unsigned short)s) << 16);
}

// ---------------------------------------------------------------------------
// Kernel 1: Gaussian filterbank masks.
//   AyF: fp32, [b][h][H]  (row-contiguous in H -> block-uniform s_loads in stage1)
//   AxT: bf16, [b][W][w]  (k-contiguous -> b128 B-frags in stage2)
// One wave per (b, axis, r).
// ---------------------------------------------------------------------------
__global__ __launch_bounds__(64) void mask_kernel(const float* __restrict__ tp,
                                                  float* __restrict__ AyF,
                                                  unsigned short* __restrict__ AxT) {
    int blk  = blockIdx.x;
    int r    = blk & 63;
    int axis = (blk >> 6) & 1;
    int b    = blk >> 7;

    const float* p = tp + b*6 + (axis ? 3 : 0);
    float u = p[0], s = p[1], d = p[2];
    float centre = u + (float)r * d;
    float inv_s  = 1.0f / s;

    int lane = threadIdx.x;
    float e[8];
    float sum = 0.0f;
    #pragma unroll
    for (int i = 0; i < 8; ++i) {
        float z = ((float)(i*64 + lane) - centre) * inv_s;
        e[i] = __expf(-0.5f * z * z);
        sum += e[i];
    }
    #pragma unroll
    for (int m = 1; m < 64; m <<= 1)
        sum += __shfl_xor(sum, m, 64);
    float inv_sum = 1.0f / (sum + 1e-8f);

    if (axis) {
        unsigned short* dst = AxT + ((size_t)b*GOUT + r) * IMG;
        #pragma unroll
        for (int i = 0; i < 8; ++i)
            dst[i*64 + lane] = f2bf(e[i] * inv_sum);
    } else {
        #pragma unroll
        for (int i = 0; i < 8; ++i)
            AyF[((size_t)b*IMG + i*64 + lane) * GOUT + r] = e[i] * inv_sum;
    }
}

// ---------------------------------------------------------------------------
// Kernel 2: gB[part][b][c][H][w] (bf16) = sum_{h in part} Ay[b,h,H]*img[b,h,wc]
// PURE-STREAM fp32 VALU (r4-r7 lesson: every MFMA variant feeds operands via
// multi-line gather instructions and pins at ~1.3 TB/s with all pipes idle —
// a scattered-line in-flight cap. This kernel's global accesses are all
// 64-lane-contiguous streams, the m13-proven 6.3 TB/s access class).
// Thread owns column wc; per h: 1 coalesced dword load + 64 v_fma with
// Ay[h][:] as block-uniform SGPR operands (s_load). acc = float4[16], fully
// unrolled (r1-proven promotion; r0's failure mode was the unpromoted form).
// Grid (b, jc, part) = 32*6*4 = 768 blocks x 256 thr = 12 waves/CU.
// VALU floor 20.5 us; HBM ~20 us.
// ---------------------------------------------------------------------------
__global__ __launch_bounds__(256) void stage1_kernel(const float* __restrict__ img,
                                                     const float* __restrict__ Ay,
                                                     unsigned short* __restrict__ gB) {
    int blk  = blockIdx.x;          // (b*6 + jc)*4 + part
    int part = blk & 3;
    int bj   = blk >> 2;
    int jc   = bj % 6;
    int b    = bj / 6;
    int wc   = jc*256 + threadIdx.x;
    int w    = wc / 3;
    int c    = wc - 3*w;

    const float* imgp = img + ((size_t)b*IMG + part*128) * ROWB + wc;
    const float* ayp  = Ay  + ((size_t)b*IMG + part*128) * GOUT;

    floatx4 acc[16];
    #pragma unroll
    for (int k = 0; k < 16; ++k) acc[k] = (floatx4){0.f, 0.f, 0.f, 0.f};

    #pragma unroll 4
    for (int h = 0; h < 128; ++h) {
        float v = imgp[(size_t)h * ROWB];
        const float* ar = ayp + (size_t)h * GOUT;   // block-uniform -> s_load
        #pragma unroll
        for (int k = 0; k < 16; ++k) {
            acc[k][0] = fmaf(ar[k*4+0], v, acc[k][0]);
            acc[k][1] = fmaf(ar[k*4+1], v, acc[k][1]);
            acc[k][2] = fmaf(ar[k*4+2], v, acc[k][2]);
            acc[k][3] = fmaf(ar[k*4+3], v, acc[k][3]);
        }
    }

    // planar bf16 partial: gB[part][b][c][H][w]
    unsigned short* gp = gB + (size_t)part*GPLANE
                       + ((size_t)(b*CH + c) * GOUT) * IMG + w;
    #pragma unroll
    for (int k = 0; k < 16; ++k)
        #pragma unroll
        for (int r = 0; r < 4; ++r)
            gp[(size_t)(k*4 + r) * IMG] = f2bf(acc[k][r]);
}

// ---------------------------------------------------------------------------
// Kernel 3: out[b,H,W,c] += sum_{w part} (sum_p gB[p])[b,c,H,w] * Ax[b,w,W]
// r6-verified MFMA logic; A-frag now sums the 4 bf16 k-partials in fp32.
// Grid (b,c,part)=384; w-split 4, fp32 atomicAdd into zeroed out.
// ---------------------------------------------------------------------------
__global__ __launch_bounds__(256) void stage2_kernel(const unsigned short* __restrict__ gB,
                                                     const unsigned short* __restrict__ AxT,
                                                     float* __restrict__ out) {
    int blk  = blockIdx.x;
    int part = blk & 3;
    int bc   = blk >> 2;
    int c    = bc % 3;
    int b    = bc / 3;
    int tid  = threadIdx.x;
    int wm   = tid >> 6;
    int lane = tid & 63;
    int n16  = lane & 15;
    int q    = lane >> 4;

    floatx4 acc[4];
    #pragma unroll
    for (int nt = 0; nt < 4; ++nt) acc[nt] = (floatx4){0.f, 0.f, 0.f, 0.f};

    const unsigned short* ga  = gB  + ((size_t)(b*CH + c) * GOUT + wm*16 + n16) * IMG;
    const unsigned short* axb = AxT + ((size_t)b*GOUT + n16) * IMG;

    #pragma unroll
    for (int cc = 0; cc < 4; ++cc) {
        int w0 = part*128 + cc*32;
        short8 s0 = *(const short8*)(ga + w0 + q*8);
        short8 s1 = *(const short8*)(ga + GPLANE   + w0 + q*8);
        short8 s2 = *(const short8*)(ga + 2*GPLANE + w0 + q*8);
        short8 s3 = *(const short8*)(ga + 3*GPLANE + w0 + q*8);
        short8 af;
        #pragma unroll
        for (int j = 0; j < 8; ++j)
            af[j] = (short)f2bf((b2f(s0[j]) + b2f(s1[j])) + (b2f(s2[j]) + b2f(s3[j])));

        #pragma unroll
        for (int nt = 0; nt < 4; ++nt) {
            short8 bf = *(const short8*)(axb + (size_t)nt*16*IMG + w0 + q*8);
            acc[nt] = __builtin_amdgcn_mfma_f32_16x16x32_bf16(af, bf, acc[nt], 0, 0, 0);
        }
    }

    #pragma unroll
    for (int nt = 0; nt < 4; ++nt) {
        int W = nt*16 + n16;
        #pragma unroll
        for (int reg = 0; reg < 4; ++reg) {
            int H = wm*16 + q*4 + reg;
            atomicAdd(out + (((size_t)b*GOUT + H) * GOUT + W) * CH + c, acc[nt][reg]);
        }
    }
}

// ---------------------------------------------------------------------------
// Workspace: AyF 4 MB fp32 | AxT 2 MB bf16 | gB 4 x 6 MB bf16  (~30 MB).
// ---------------------------------------------------------------------------
extern "C" void kernel_launch(void* const* d_in, const int* in_sizes, int n_in,
                              void* d_out, int out_size, void* d_ws, size_t ws_size,
                              hipStream_t stream) {
    const float* img = (const float*)d_in[0];
    const float* tp  = (const float*)d_in[1];
    float* out = (float*)d_out;

    float*          AyF = (float*)d_ws;
    unsigned short* AxT = (unsigned short*)(AyF + (size_t)BATCH * IMG * GOUT);
    unsigned short* gB  = AxT + (size_t)BATCH * GOUT * IMG;

    hipMemsetAsync(d_out, 0, (size_t)out_size * sizeof(float), stream);
    mask_kernel  <<<BATCH * 2 * GOUT,  64, 0, stream>>>(tp, AyF, AxT);
    stage1_kernel<<<BATCH * 6 * 4,    256, 0, stream>>>(img, AyF, gB);
    stage2_kernel<<<BATCH * CH * 4,   256, 0, stream>>>(gB, AxT, out);
}